// Round 1
// baseline (123.733 us; speedup 1.0000x reference)
//
#include <hip/hip_runtime.h>
#include <hip/hip_bf16.h>
#include <math.h>

#define N_TOK 8192
#define D 512
#define NE 8

typedef float f32x4 __attribute__((ext_vector_type(4)));
typedef __bf16 bf16x8 __attribute__((ext_vector_type(8)));
typedef unsigned short u16;
typedef u16 u16x8 __attribute__((ext_vector_type(8)));

// ---- workspace layout (bytes) ----
// 0        int   count[8]
// 64       float imp[8]
// 256      int   tok_e[2*N_TOK]    (64 KB)
// 65792    float tok_g[2*N_TOK]    (64 KB)
// 131328   int   bucket[NE*N_TOK]  (256 KB)
// 1 MB     u16   xb[N_TOK*D]       (8 MB)   x in bf16
// 9 MB     u16   ewt[NE*D*D]       (4 MB)   expert_w [e][f][d] bf16
// 13 MB    u16   y[2*N_TOK*D]      (16 MB)  per-slot expert outputs bf16
#define OFF_TOKE  256
#define OFF_TOKG  65792
#define OFF_BUCK  131328
#define OFF_XB    (1u << 20)
#define OFF_EWT   (OFF_XB + 8u * 1024 * 1024)
#define OFF_Y     (OFF_EWT + 4u * 1024 * 1024)

__device__ __forceinline__ u16 f2b(float v) {
    __hip_bfloat16 h = __float2bfloat16(v);
    return *reinterpret_cast<u16*>(&h);
}
__device__ __forceinline__ float b2f(u16 u) {
    __hip_bfloat16 h;
    *reinterpret_cast<u16*>(&h) = u;
    return __bfloat162float(h);
}

typedef __attribute__((address_space(1))) const void* gp1_t;
typedef __attribute__((address_space(3))) void* lp3_t;
__device__ __forceinline__ void gload16(const void* g, void* l) {
    __builtin_amdgcn_global_load_lds((gp1_t)g, (lp3_t)l, 16, 0, 0);
}

// -------- fused: gate (blocks 0..2047) | prep_w transpose (blocks 2048..2559)
// NOTE: no count/imp zero-init here — that is done by hipMemsetAsync (round-3
// post-mortem: kernel-store zeroing consumed by next-kernel atomics diverged
// on graph replay; memset zeroing is the replay-proven path).
__global__ __launch_bounds__(256) void gate_prep_kernel(
    const float* __restrict__ x, const float* __restrict__ wg,
    const float* __restrict__ ew,
    int* __restrict__ tok_e, float* __restrict__ tok_g, u16* __restrict__ xb,
    u16* __restrict__ ewt)
{
    __shared__ __align__(16) float sbuf[64 * 65];   // 16.6 KB, both paths
    int b = blockIdx.x;
    int tid = threadIdx.x;

    if (b >= 2048) {
        // ---- prep path: expert_w [e][d][f] fp32 -> ewt [e][f][d] bf16
        int pb = b - 2048;
        float (*tile)[65] = (float(*)[65])sbuf;
        int e = pb >> 6, dt = (pb >> 3) & 7, ftl = pb & 7;
        int c = tid & 63, rq = tid >> 6;
        const float* src = ew + (size_t)e * D * D + (size_t)(dt * 64) * D + ftl * 64;
#pragma unroll
        for (int i = 0; i < 16; ++i) {
            int r = i * 4 + rq;
            tile[r][c] = src[(size_t)r * D + c];
        }
        __syncthreads();
        u16* dst = ewt + (size_t)e * D * D + (size_t)(ftl * 64) * D + dt * 64;
#pragma unroll
        for (int i = 0; i < 16; ++i) {
            int f = i * 4 + rq;
            dst[(size_t)f * D + c] = f2b(tile[c][f]);
        }
        return;
    }

    // ---- gate path
    float* wgs = sbuf;   // [e][d] transposed, conflict-free
    for (int i = tid; i < NE * D; i += 256) {
        int d = i >> 3, e = i & 7;   // w_gate flat = d*8 + e
        wgs[e * D + d] = wg[i];
    }
    __syncthreads();

    int wave = tid >> 6, lane = tid & 63;
    int n = b * 4 + wave;
    const float* xr = x + (size_t)n * D;
    u16* xbr = xb + (size_t)n * D;

    float p[NE];
#pragma unroll
    for (int e = 0; e < NE; ++e) p[e] = 0.f;
#pragma unroll
    for (int it = 0; it < 8; ++it) {
        float xv = xr[it * 64 + lane];
        xbr[it * 64 + lane] = f2b(xv);
#pragma unroll
        for (int e = 0; e < NE; ++e)
            p[e] += xv * wgs[e * D + it * 64 + lane];
    }
#pragma unroll
    for (int off = 32; off > 0; off >>= 1) {
#pragma unroll
        for (int e = 0; e < NE; ++e)
            p[e] += __shfl_xor(p[e], off);
    }

    if (lane == 0) {
        // top-2, ties -> lowest index (jax.lax.top_k semantics)
        int e1 = 0; float v1 = p[0];
#pragma unroll
        for (int e = 1; e < NE; ++e) if (p[e] > v1) { v1 = p[e]; e1 = e; }
        int e2 = -1; float v2 = -INFINITY;
#pragma unroll
        for (int e = 0; e < NE; ++e) if (e != e1 && p[e] > v2) { v2 = p[e]; e2 = e; }
        float t = __expf(v2 - v1);
        float inv = 1.f / (1.f + t);
        tok_e[2 * n] = e1;     tok_e[2 * n + 1] = e2;
        tok_g[2 * n] = inv;    tok_g[2 * n + 1] = t * inv;
    }
}

// -------- bucketize: two-level offsets, 512 global atomics (round-2 proven)
__global__ __launch_bounds__(256) void bucketize_kernel(
    const int* __restrict__ tok_e, const float* __restrict__ tok_g,
    int* __restrict__ count, float* __restrict__ imp, int* __restrict__ bucket)
{
    __shared__ int lcnt[NE], lbase[NE];
    __shared__ float limp[NE];
    int tid = threadIdx.x;
    if (tid < NE) { lcnt[tid] = 0; limp[tid] = 0.f; }
    __syncthreads();

    int n = blockIdx.x * 256 + tid;
    int e1 = tok_e[2 * n], e2 = tok_e[2 * n + 1];
    float g1 = tok_g[2 * n], g2 = tok_g[2 * n + 1];
    int o1 = atomicAdd(&lcnt[e1], 1);
    int o2 = atomicAdd(&lcnt[e2], 1);
    atomicAdd(&limp[e1], g1);
    atomicAdd(&limp[e2], g2);
    __syncthreads();
    if (tid < NE) {
        lbase[tid] = atomicAdd(&count[tid], lcnt[tid]);
        atomicAdd(&imp[tid], limp[tid]);
    }
    __syncthreads();
    bucket[e1 * N_TOK + lbase[e1] + o1] = 2 * n;
    bucket[e2 * N_TOK + lbase[e2] + o2] = 2 * n + 1;
}

// -------- grouped GEMM, bf16 MFMA 16x16x32, 128x128 tile, BK=32
// Round-1 change: double-buffered LDS + counted-vmcnt prefetch (T3-minimum,
// learn_hip §5.5 recipe). Old structure exposed full global->LDS latency per
// K-step (barrier; load; barrier-with-vmcnt(0)-drain; compute). New structure
// issues next tile's 4 global_load_lds BEFORE computing current, waits
// s_waitcnt vmcnt(4) (counted — prefetch stays in flight across the barrier),
// raw s_barrier (NOT __syncthreads, which would drain vmcnt(0)).
__global__ __launch_bounds__(256) void moe_gemm(
    const u16* __restrict__ xb, const u16* __restrict__ ewt,
    const int* __restrict__ count, const int* __restrict__ bucket,
    u16* __restrict__ y)
{
    int b = blockIdx.x;
    int ft = b & 3;            // feature tile (128 cols)
    int tt = (b >> 2) & 63;    // token tile (128 slots)
    int e  = b >> 8;           // expert
    int cnt = count[e];
    if (tt * 128 >= cnt) return;

    __shared__ int sl[128];
    // double-buffer: buf p at smem + p*8192; As [128][32] | Bs [128][32] u16.
    // epilogue union: 4 x (32 x 72) u16 = 9216 u16 fits in buffer 0+.
    __shared__ __align__(16) u16 smem[16384];       // 32 KB

    int tid = threadIdx.x;
    if (tid < 128) {
        int idx = tt * 128 + tid;
        sl[tid] = (idx < cnt) ? bucket[e * N_TOK + idx] : -1;
    }
    __syncthreads();

    int w = tid >> 6, l = tid & 63;
    int c8 = (l & 3) * 8;
    int r0 = w * 32 + (l >> 2);
    int r1 = r0 + 16;
    int s0 = sl[r0], s1 = sl[r1];
    int ta0 = (s0 < 0) ? 0 : (s0 >> 1);
    int ta1 = (s1 < 0) ? 0 : (s1 >> 1);
    const u16* gA0 = xb + (size_t)ta0 * D + c8;
    const u16* gA1 = xb + (size_t)ta1 * D + c8;
    const u16* gB0 = ewt + ((size_t)e * D + ft * 128 + r0) * D + c8;
    const u16* gB1 = ewt + ((size_t)e * D + ft * 128 + r1) * D + c8;

    int wm = w & 1, wn = w >> 1;    // 2x2 waves, each 64x64 out
    int lm = l & 15, quad = l >> 4, kq = quad * 8;

    f32x4 acc[4][4] = {};

    // stage K-tile kc into buffer p (wave-uniform LDS dest, per-lane global src)
    auto stage = [&](int p, int kc) {
        u16* As = smem + p * 8192;
        u16* Bs = As + 4096;
        gload16(gA0 + kc * 32, &As[(w * 32) * 32]);
        gload16(gA1 + kc * 32, &As[(w * 32 + 16) * 32]);
        gload16(gB0 + kc * 32, &Bs[(w * 32) * 32]);
        gload16(gB1 + kc * 32, &Bs[(w * 32 + 16) * 32]);
    };

    stage(0, 0);                    // prologue prefetch
    int cur = 0;
    for (int kc = 0; kc < 16; ++kc) {
        if (kc < 15) {
            stage(cur ^ 1, kc + 1);                         // prefetch next
            asm volatile("s_waitcnt vmcnt(4)" ::: "memory"); // cur's 4 done, next's 4 in flight
        } else {
            asm volatile("s_waitcnt vmcnt(0)" ::: "memory");
        }
        __builtin_amdgcn_s_barrier();     // all waves' cur loads visible
        asm volatile("" ::: "memory");    // no LDS-read hoist above barrier

        const u16* As = smem + cur * 8192;
        const u16* Bs = As + 4096;
        bf16x8 af[4], bfv[4];
#pragma unroll
        for (int i = 0; i < 4; ++i)
            af[i] = *(const bf16x8*)&As[(wm * 64 + i * 16 + lm) * 32 + kq];
#pragma unroll
        for (int j = 0; j < 4; ++j)
            bfv[j] = *(const bf16x8*)&Bs[(wn * 64 + j * 16 + lm) * 32 + kq];
#pragma unroll
        for (int i = 0; i < 4; ++i)
#pragma unroll
            for (int j = 0; j < 4; ++j)
                acc[i][j] = __builtin_amdgcn_mfma_f32_16x16x32_bf16(
                    af[i], bfv[j], acc[i][j], 0, 0, 0);

        // own ds_reads complete + compiler fence, then barrier: next iter's
        // stage may overwrite cur only after ALL waves finished reading it.
        asm volatile("s_waitcnt lgkmcnt(0)" ::: "memory");
        __builtin_amdgcn_s_barrier();
        cur ^= 1;
    }

    // ---- epilogue: per-wave LDS transpose, then coalesced 16B stores.
    // C/D layout (m89): col = lane&15, row = quad*4 + reg.
    __syncthreads();                 // full fence before repurposing smem
    u16* Es = smem + w * 2304;       // 32 rows x 72 u16, 16B-aligned rows
#pragma unroll
    for (int h = 0; h < 2; ++h) {
#pragma unroll
        for (int i2 = 0; i2 < 2; ++i2) {
            int i = h * 2 + i2;
#pragma unroll
            for (int j = 0; j < 4; ++j)
#pragma unroll
                for (int r = 0; r < 4; ++r)
                    Es[(i2 * 16 + quad * 4 + r) * 72 + j * 16 + lm] =
                        f2b(acc[i][j][r]);
        }
        int row = l >> 1, hc = l & 1;        // 2 lanes per row, 64B halves
        int s = sl[wm * 64 + h * 32 + row];
        const u16* src = Es + row * 72 + hc * 32;
        u16* dst = y + (size_t)((s < 0) ? 0 : s) * D + ft * 128 + wn * 64 + hc * 32;
        if (s >= 0) {
#pragma unroll
            for (int c = 0; c < 4; ++c)
                *(u16x8*)(dst + c * 8) = *(const u16x8*)(src + c * 8);
        }
        __syncthreads();   // Es reused across h; keep waves in step
    }
}

// -------- combine (blocks 0..4095) | loss (block 4096)
__global__ __launch_bounds__(256) void combine_kernel(
    const u16* __restrict__ y, const float* __restrict__ tok_g,
    const int* __restrict__ count, const float* __restrict__ imp,
    float* __restrict__ out)
{
    if (blockIdx.x == 4096) {
        if (threadIdx.x == 0) {
            float mi = 0.f, ml = 0.f;
            for (int e = 0; e < NE; ++e) { mi += imp[e]; ml += (float)count[e]; }
            mi *= 0.125f; ml *= 0.125f;
            float vi = 0.f, vl = 0.f;
            for (int e = 0; e < NE; ++e) {
                float di = imp[e] - mi;          vi += di * di;
                float dl = (float)count[e] - ml; vl += dl * dl;
            }
            vi *= 0.125f; vl *= 0.125f;
            out[N_TOK * D] = vi / (mi * mi + 1e-10f) + vl / (ml * ml + 1e-10f);
        }
        return;
    }
    int idx = blockIdx.x * 256 + threadIdx.x;
    int n = idx >> 7;
    int c = (idx & 127) * 4;
    const ushort4 ua = *(const ushort4*)(y + (size_t)(2 * n) * D + c);
    const ushort4 ub = *(const ushort4*)(y + (size_t)(2 * n + 1) * D + c);
    float g1 = tok_g[2 * n], g2 = tok_g[2 * n + 1];
    const float eps = 2.2204460492503131e-16f;
    float4 r;
    float v;
    v = g1 * __expf(b2f(ua.x)) + g2 * __expf(b2f(ub.x)); r.x = __logf(v == 0.f ? eps : v);
    v = g1 * __expf(b2f(ua.y)) + g2 * __expf(b2f(ub.y)); r.y = __logf(v == 0.f ? eps : v);
    v = g1 * __expf(b2f(ua.z)) + g2 * __expf(b2f(ub.z)); r.z = __logf(v == 0.f ? eps : v);
    v = g1 * __expf(b2f(ua.w)) + g2 * __expf(b2f(ub.w)); r.w = __logf(v == 0.f ? eps : v);
    *(float4*)(out + (size_t)n * D + c) = r;
}

extern "C" void kernel_launch(void* const* d_in, const int* in_sizes, int n_in,
                              void* d_out, int out_size, void* d_ws, size_t ws_size,
                              hipStream_t stream)
{
    const float* x  = (const float*)d_in[0];
    const float* wg = (const float*)d_in[1];
    const float* ew = (const float*)d_in[2];
    char* ws = (char*)d_ws;
    int*   count  = (int*)(ws + 0);
    float* imp    = (float*)(ws + 64);
    int*   tok_e  = (int*)(ws + OFF_TOKE);
    float* tok_g  = (float*)(ws + OFF_TOKG);
    int*   bucket = (int*)(ws + OFF_BUCK);
    u16*   xb     = (u16*)(ws + OFF_XB);
    u16*   ewt    = (u16*)(ws + OFF_EWT);
    u16*   y      = (u16*)(ws + OFF_Y);
    float* out    = (float*)d_out;

    hipMemsetAsync(ws, 0, 128, stream);   // count + imp (replay-proven path)
    gate_prep_kernel<<<2048 + 512, 256, 0, stream>>>(x, wg, ew, tok_e, tok_g, xb, ewt);
    bucketize_kernel<<<N_TOK / 256, 256, 0, stream>>>(tok_e, tok_g, count, imp, bucket);
    moe_gemm<<<NE * 64 * 4, 256, 0, stream>>>(xb, ewt, count, bucket, y);
    combine_kernel<<<4097, 256, 0, stream>>>(y, tok_g, count, imp, out);
}

// Round 2
// 118.509 us; speedup vs baseline: 1.0441x; 1.0441x over previous
//
#include <hip/hip_runtime.h>
#include <hip/hip_bf16.h>
#include <math.h>

#define N_TOK 8192
#define D 512
#define NE 8

typedef float f32x4 __attribute__((ext_vector_type(4)));
typedef __bf16 bf16x8 __attribute__((ext_vector_type(8)));
typedef unsigned short u16;
typedef u16 u16x8 __attribute__((ext_vector_type(8)));

// ---- workspace layout (bytes) ----
// 0        int   count[8]
// 64       float imp[8]
// 256      int   tok_e[2*N_TOK]    (64 KB)
// 65792    float tok_g[2*N_TOK]    (64 KB)
// 131328   int   bucket[NE*N_TOK]  (256 KB)
// 1 MB     u16   xb[N_TOK*D]       (8 MB)   x in bf16
// 9 MB     u16   ewt[NE*D*D]       (4 MB)   expert_w [e][f][d] bf16
// 13 MB    u16   y[2*N_TOK*D]      (16 MB)  per-slot expert outputs bf16
#define OFF_TOKE  256
#define OFF_TOKG  65792
#define OFF_BUCK  131328
#define OFF_XB    (1u << 20)
#define OFF_EWT   (OFF_XB + 8u * 1024 * 1024)
#define OFF_Y     (OFF_EWT + 4u * 1024 * 1024)

__device__ __forceinline__ u16 f2b(float v) {
    __hip_bfloat16 h = __float2bfloat16(v);
    return *reinterpret_cast<u16*>(&h);
}
__device__ __forceinline__ float b2f(u16 u) {
    __hip_bfloat16 h;
    *reinterpret_cast<u16*>(&h) = u;
    return __bfloat162float(h);
}

typedef __attribute__((address_space(1))) const void* gp1_t;
typedef __attribute__((address_space(3))) void* lp3_t;
__device__ __forceinline__ void gload16(const void* g, void* l) {
    __builtin_amdgcn_global_load_lds((gp1_t)g, (lp3_t)l, 16, 0, 0);
}

// -------- fused: gate (blocks 0..511, 16 tok/block) | prep_w (blocks 512..1023)
// R2: gate amortization — 4x fewer blocks, each w_gate LDS fill now serves 16
// tokens; x loaded as float4 (16B/lane), w_gate read as b128 (bank-uniform).
// NOTE: no count/imp zero-init here — hipMemsetAsync does it (replay-proven).
__global__ __launch_bounds__(256) void gate_prep_kernel(
    const float* __restrict__ x, const float* __restrict__ wg,
    const float* __restrict__ ew,
    int* __restrict__ tok_e, float* __restrict__ tok_g, u16* __restrict__ xb,
    u16* __restrict__ ewt)
{
    __shared__ __align__(16) float sbuf[64 * 65];   // 16.6 KB, both paths
    int b = blockIdx.x;
    int tid = threadIdx.x;

    if (b >= 512) {
        // ---- prep path: expert_w [e][d][f] fp32 -> ewt [e][f][d] bf16
        int pb = b - 512;
        float (*tile)[65] = (float(*)[65])sbuf;
        int e = pb >> 6, dt = (pb >> 3) & 7, ftl = pb & 7;
        int c = tid & 63, rq = tid >> 6;
        const float* src = ew + (size_t)e * D * D + (size_t)(dt * 64) * D + ftl * 64;
#pragma unroll
        for (int i = 0; i < 16; ++i) {
            int r = i * 4 + rq;
            tile[r][c] = src[(size_t)r * D + c];
        }
        __syncthreads();
        u16* dst = ewt + (size_t)e * D * D + (size_t)(ftl * 64) * D + dt * 64;
#pragma unroll
        for (int i = 0; i < 16; ++i) {
            int f = i * 4 + rq;
            dst[(size_t)f * D + c] = f2b(tile[c][f]);
        }
        return;
    }

    // ---- gate path: 16 tokens per block (4 per wave)
    float* wgs = sbuf;   // [e][d] transposed, conflict-free scalar & b128 reads
    for (int i = tid; i < NE * D; i += 256) {
        int d = i >> 3, e = i & 7;   // w_gate flat = d*8 + e
        wgs[e * D + d] = wg[i];
    }
    __syncthreads();

    int wave = tid >> 6, lane = tid & 63;
#pragma unroll
    for (int t = 0; t < 4; ++t) {
        int n = b * 16 + wave * 4 + t;
        const float4* xr4 = (const float4*)(x + (size_t)n * D);
        ushort4* xb4 = (ushort4*)(xb + (size_t)n * D);

        float p[NE];
#pragma unroll
        for (int e = 0; e < NE; ++e) p[e] = 0.f;
#pragma unroll
        for (int it = 0; it < 2; ++it) {
            float4 v = xr4[it * 64 + lane];
            ushort4 s;
            s.x = f2b(v.x); s.y = f2b(v.y); s.z = f2b(v.z); s.w = f2b(v.w);
            xb4[it * 64 + lane] = s;
#pragma unroll
            for (int e = 0; e < NE; ++e) {
                float4 wv = *(const float4*)&wgs[e * D + (it * 64 + lane) * 4];
                p[e] += v.x * wv.x + v.y * wv.y + v.z * wv.z + v.w * wv.w;
            }
        }
#pragma unroll
        for (int off = 32; off > 0; off >>= 1) {
#pragma unroll
            for (int e = 0; e < NE; ++e)
                p[e] += __shfl_xor(p[e], off);
        }

        if (lane == 0) {
            // top-2, ties -> lowest index (jax.lax.top_k semantics)
            int e1 = 0; float v1 = p[0];
#pragma unroll
            for (int e = 1; e < NE; ++e) if (p[e] > v1) { v1 = p[e]; e1 = e; }
            int e2 = -1; float v2 = -INFINITY;
#pragma unroll
            for (int e = 0; e < NE; ++e) if (e != e1 && p[e] > v2) { v2 = p[e]; e2 = e; }
            float tv = __expf(v2 - v1);
            float inv = 1.f / (1.f + tv);
            tok_e[2 * n] = e1;     tok_e[2 * n + 1] = e2;
            tok_g[2 * n] = inv;    tok_g[2 * n + 1] = tv * inv;
        }
    }
}

// -------- bucketize: two-level offsets, 512 global atomics (round-2 proven)
__global__ __launch_bounds__(256) void bucketize_kernel(
    const int* __restrict__ tok_e, const float* __restrict__ tok_g,
    int* __restrict__ count, float* __restrict__ imp, int* __restrict__ bucket)
{
    __shared__ int lcnt[NE], lbase[NE];
    __shared__ float limp[NE];
    int tid = threadIdx.x;
    if (tid < NE) { lcnt[tid] = 0; limp[tid] = 0.f; }
    __syncthreads();

    int n = blockIdx.x * 256 + tid;
    int e1 = tok_e[2 * n], e2 = tok_e[2 * n + 1];
    float g1 = tok_g[2 * n], g2 = tok_g[2 * n + 1];
    int o1 = atomicAdd(&lcnt[e1], 1);
    int o2 = atomicAdd(&lcnt[e2], 1);
    atomicAdd(&limp[e1], g1);
    atomicAdd(&limp[e2], g2);
    __syncthreads();
    if (tid < NE) {
        lbase[tid] = atomicAdd(&count[tid], lcnt[tid]);
        atomicAdd(&imp[tid], limp[tid]);
    }
    __syncthreads();
    bucket[e1 * N_TOK + lbase[e1] + o1] = 2 * n;
    bucket[e2 * N_TOK + lbase[e2] + o2] = 2 * n + 1;
}

// -------- grouped GEMM, bf16 MFMA 16x16x32, 128x128 tile, BK=32
// R2: triple-buffered LDS (48 KB, 3 blocks/CU) -> ONE barrier per K-step.
// Invariant: stage of tile k+2 (issued just after barrier k) overwrites the
// buffer read at step k-1; every wave executes s_waitcnt lgkmcnt(0) before
// barrier k, so all ds_reads of step k-1 are retired chip-wide when any wave
// passes barrier k. vmcnt(4) keeps the next tile's 4 loads in flight (T4).
// T5 setprio around the MFMA cluster.
__global__ __launch_bounds__(256) void moe_gemm(
    const u16* __restrict__ xb, const u16* __restrict__ ewt,
    const int* __restrict__ count, const int* __restrict__ bucket,
    u16* __restrict__ y)
{
    int b = blockIdx.x;
    int ft = b & 3;            // feature tile (128 cols)
    int tt = (b >> 2) & 63;    // token tile (128 slots)
    int e  = b >> 8;           // expert
    int cnt = count[e];
    if (tt * 128 >= cnt) return;

    __shared__ int sl[128];
    // 3 bufs at smem + p*8192: As [128][32] | Bs [128][32] (u16).
    // epilogue union: 4 x (32 x 72) u16 = 9216 u16, reuses smem.
    __shared__ __align__(16) u16 smem[24576];       // 48 KB

    int tid = threadIdx.x;
    if (tid < 128) {
        int idx = tt * 128 + tid;
        sl[tid] = (idx < cnt) ? bucket[e * N_TOK + idx] : -1;
    }
    __syncthreads();

    int w = tid >> 6, l = tid & 63;
    int c8 = (l & 3) * 8;
    int r0 = w * 32 + (l >> 2);
    int r1 = r0 + 16;
    int s0 = sl[r0], s1 = sl[r1];
    int ta0 = (s0 < 0) ? 0 : (s0 >> 1);
    int ta1 = (s1 < 0) ? 0 : (s1 >> 1);
    const u16* gA0 = xb + (size_t)ta0 * D + c8;
    const u16* gA1 = xb + (size_t)ta1 * D + c8;
    const u16* gB0 = ewt + ((size_t)e * D + ft * 128 + r0) * D + c8;
    const u16* gB1 = ewt + ((size_t)e * D + ft * 128 + r1) * D + c8;

    int wm = w & 1, wn = w >> 1;    // 2x2 waves, each 64x64 out
    int lm = l & 15, quad = l >> 4, kq = quad * 8;

    f32x4 acc[4][4] = {};

    // stage K-tile kc into buffer p (wave-uniform LDS dest, per-lane global src)
    auto stage = [&](int p, int kc) {
        u16* As = smem + p * 8192;
        u16* Bs = As + 4096;
        gload16(gA0 + kc * 32, &As[(w * 32) * 32]);
        gload16(gA1 + kc * 32, &As[(w * 32 + 16) * 32]);
        gload16(gB0 + kc * 32, &Bs[(w * 32) * 32]);
        gload16(gB1 + kc * 32, &Bs[(w * 32 + 16) * 32]);
    };

    stage(0, 0);
    stage(1, 1);
    int bi = 0, bj = 2;
    for (int kc = 0; kc < 16; ++kc) {
        // own tile-kc loads landed + own ds_reads retired, THEN barrier:
        // all waves past barrier => tile kc fully staged, buf (kc-1)%3 idle.
        if (kc < 15)
            asm volatile("s_waitcnt vmcnt(4) lgkmcnt(0)" ::: "memory");
        else
            asm volatile("s_waitcnt vmcnt(0) lgkmcnt(0)" ::: "memory");
        __builtin_amdgcn_s_barrier();
        asm volatile("" ::: "memory");

        if (kc < 14) {
            stage(bj, kc + 2);            // overwrites buf (kc-1)%3 — safe
            bj = (bj == 2) ? 0 : bj + 1;
        }

        const u16* As = smem + bi * 8192;
        const u16* Bs = As + 4096;
        bi = (bi == 2) ? 0 : bi + 1;

        bf16x8 af[4], bfv[4];
#pragma unroll
        for (int i = 0; i < 4; ++i)
            af[i] = *(const bf16x8*)&As[(wm * 64 + i * 16 + lm) * 32 + kq];
#pragma unroll
        for (int j = 0; j < 4; ++j)
            bfv[j] = *(const bf16x8*)&Bs[(wn * 64 + j * 16 + lm) * 32 + kq];

        __builtin_amdgcn_s_setprio(1);
#pragma unroll
        for (int i = 0; i < 4; ++i)
#pragma unroll
            for (int j = 0; j < 4; ++j)
                acc[i][j] = __builtin_amdgcn_mfma_f32_16x16x32_bf16(
                    af[i], bfv[j], acc[i][j], 0, 0, 0);
        __builtin_amdgcn_s_setprio(0);
    }

    // ---- epilogue: per-wave LDS transpose, then coalesced 16B stores.
    // C/D layout (m89): col = lane&15, row = quad*4 + reg.
    __syncthreads();                 // full fence before repurposing smem
    u16* Es = smem + w * 2304;       // 32 rows x 72 u16, 16B-aligned rows
#pragma unroll
    for (int h = 0; h < 2; ++h) {
#pragma unroll
        for (int i2 = 0; i2 < 2; ++i2) {
            int i = h * 2 + i2;
#pragma unroll
            for (int j = 0; j < 4; ++j)
#pragma unroll
                for (int r = 0; r < 4; ++r)
                    Es[(i2 * 16 + quad * 4 + r) * 72 + j * 16 + lm] =
                        f2b(acc[i][j][r]);
        }
        int row = l >> 1, hc = l & 1;        // 2 lanes per row, 64B halves
        int s = sl[wm * 64 + h * 32 + row];
        const u16* src = Es + row * 72 + hc * 32;
        u16* dst = y + (size_t)((s < 0) ? 0 : s) * D + ft * 128 + wn * 64 + hc * 32;
        if (s >= 0) {
#pragma unroll
            for (int c = 0; c < 4; ++c)
                *(u16x8*)(dst + c * 8) = *(const u16x8*)(src + c * 8);
        }
        __syncthreads();   // Es reused across h; keep waves in step
    }
}

// -------- combine (blocks 0..2047, u16x8 = 16B/lane) | loss (block 2048)
__global__ __launch_bounds__(256) void combine_kernel(
    const u16* __restrict__ y, const float* __restrict__ tok_g,
    const int* __restrict__ count, const float* __restrict__ imp,
    float* __restrict__ out)
{
    if (blockIdx.x == 2048) {
        if (threadIdx.x == 0) {
            float mi = 0.f, ml = 0.f;
            for (int e = 0; e < NE; ++e) { mi += imp[e]; ml += (float)count[e]; }
            mi *= 0.125f; ml *= 0.125f;
            float vi = 0.f, vl = 0.f;
            for (int e = 0; e < NE; ++e) {
                float di = imp[e] - mi;          vi += di * di;
                float dl = (float)count[e] - ml; vl += dl * dl;
            }
            vi *= 0.125f; vl *= 0.125f;
            out[N_TOK * D] = vi / (mi * mi + 1e-10f) + vl / (ml * ml + 1e-10f);
        }
        return;
    }
    int idx = blockIdx.x * 256 + threadIdx.x;
    int n = idx >> 6;
    int c = (idx & 63) * 8;
    const u16x8 ua = *(const u16x8*)(y + (size_t)(2 * n) * D + c);
    const u16x8 ub = *(const u16x8*)(y + (size_t)(2 * n + 1) * D + c);
    float g1 = tok_g[2 * n], g2 = tok_g[2 * n + 1];
    const float eps = 2.2204460492503131e-16f;
    float r[8];
#pragma unroll
    for (int k = 0; k < 8; ++k) {
        float v = g1 * __expf(b2f(ua[k])) + g2 * __expf(b2f(ub[k]));
        r[k] = __logf(v == 0.f ? eps : v);
    }
    float* o = out + (size_t)n * D + c;
    *(float4*)o       = make_float4(r[0], r[1], r[2], r[3]);
    *(float4*)(o + 4) = make_float4(r[4], r[5], r[6], r[7]);
}

extern "C" void kernel_launch(void* const* d_in, const int* in_sizes, int n_in,
                              void* d_out, int out_size, void* d_ws, size_t ws_size,
                              hipStream_t stream)
{
    const float* x  = (const float*)d_in[0];
    const float* wg = (const float*)d_in[1];
    const float* ew = (const float*)d_in[2];
    char* ws = (char*)d_ws;
    int*   count  = (int*)(ws + 0);
    float* imp    = (float*)(ws + 64);
    int*   tok_e  = (int*)(ws + OFF_TOKE);
    float* tok_g  = (float*)(ws + OFF_TOKG);
    int*   bucket = (int*)(ws + OFF_BUCK);
    u16*   xb     = (u16*)(ws + OFF_XB);
    u16*   ewt    = (u16*)(ws + OFF_EWT);
    u16*   y      = (u16*)(ws + OFF_Y);
    float* out    = (float*)d_out;

    hipMemsetAsync(ws, 0, 128, stream);   // count + imp (replay-proven path)
    gate_prep_kernel<<<512 + 512, 256, 0, stream>>>(x, wg, ew, tok_e, tok_g, xb, ewt);
    bucketize_kernel<<<N_TOK / 256, 256, 0, stream>>>(tok_e, tok_g, count, imp, bucket);
    moe_gemm<<<NE * 64 * 4, 256, 0, stream>>>(xb, ewt, count, bucket, y);
    combine_kernel<<<2049, 256, 0, stream>>>(y, tok_g, count, imp, out);
}